// Round 9
// baseline (353.141 us; speedup 1.0000x reference)
//
#include <hip/hip_runtime.h>
#include <hip/hip_bf16.h>

#define N_NODES 100000
#define E_EDGES 1600000
#define IN_DIM  128
#define HID     64
#define HEADS   4
#define NEG_SLOPE 0.2f
#define LN_EPS  1e-5f
#define LOG2E   1.4426950408889634f

#define BUCK_SHIFT 7
#define NODES_PER_BUCK 128
#define NBUCK ((N_NODES + NODES_PER_BUCK - 1) / NODES_PER_BUCK)   // 782
#define NBUCK_PAD 1024
#define PART_CHUNK 8192
#define HIST_BLOCKS 256

typedef float f2v __attribute__((ext_vector_type(2)));

__device__ __forceinline__ float bflo(unsigned u) { return __uint_as_float(u << 16); }
__device__ __forceinline__ float bfhi(unsigned u) { return __uint_as_float(u & 0xffff0000u); }
__device__ __forceinline__ f2v unp2(unsigned u) {
    f2v r; r.x = __uint_as_float(u << 16); r.y = __uint_as_float(u & 0xffff0000u); return r;
}
__device__ __forceinline__ unsigned packbf2(float a, float b) {
    unsigned ua = __float_as_uint(a), ub = __float_as_uint(b);
    ua += 0x7fffu + ((ua >> 16) & 1u);
    ub += 0x7fffu + ((ub >> 16) & 1u);
    return (ua >> 16) | (ub & 0xffff0000u);
}
// e pre-scaled by LOG2E; weight = exp(lrelu(e_orig)) = 2^(lrelu(e))
__device__ __forceinline__ float lrexp2(float e) {
    return __builtin_amdgcn_exp2f(fmaxf(e, NEG_SLOPE * e));
}

// ---- fused: h0 = relu(x @ Win + bin); hl0(bf16) = h0 @ Wg0; alpha0 ----
__global__ __launch_bounds__(256) void k_in_proj_fused(
        const float* __restrict__ x, const float* __restrict__ W,
        const float* __restrict__ bias,
        const float* __restrict__ W2g, const float* __restrict__ as_w,
        const float* __restrict__ ad_w,
        float* __restrict__ h, unsigned* __restrict__ hlb,
        float* __restrict__ as_o, float* __restrict__ ad_o) {
    __shared__ float Xs[32][132];     // reused as H2[32][68] later
    __shared__ float Ws[128][64];
    __shared__ float W2[64][64];
    int t = threadIdx.x;
    const float4* W4 = (const float4*)W;
    float4* Ws4 = (float4*)&Ws[0][0];
    #pragma unroll
    for (int i = 0; i < 8; ++i) Ws4[t + 256 * i] = W4[t + 256 * i];
    const float4* W24 = (const float4*)W2g;
    float4* W2s4 = (float4*)&W2[0][0];
    #pragma unroll
    for (int i = 0; i < 4; ++i) W2s4[t + 256 * i] = W24[t + 256 * i];
    int base = blockIdx.x * 32;
    const float4* X4 = (const float4*)(x + (size_t)base * IN_DIM);
    #pragma unroll
    for (int i = 0; i < 4; ++i) {
        int f = t + 256 * i;
        int row = f >> 5, col4 = f & 31;
        ((float4*)&Xs[row][0])[col4] = X4[f];
    }
    __syncthreads();
    int r = t >> 4;
    int c = (t & 15) * 4;
    float4 bb = *(const float4*)(bias + c);
    float4 acc0 = bb, acc1 = bb;
    #pragma unroll 8
    for (int k = 0; k < 128; ++k) {
        float a0 = Xs[r][k];
        float a1 = Xs[r + 16][k];
        float4 b = *(const float4*)&Ws[k][c];
        acc0.x += a0 * b.x; acc0.y += a0 * b.y; acc0.z += a0 * b.z; acc0.w += a0 * b.w;
        acc1.x += a1 * b.x; acc1.y += a1 * b.y; acc1.z += a1 * b.z; acc1.w += a1 * b.w;
    }
    acc0.x = fmaxf(acc0.x, 0.f); acc0.y = fmaxf(acc0.y, 0.f);
    acc0.z = fmaxf(acc0.z, 0.f); acc0.w = fmaxf(acc0.w, 0.f);
    acc1.x = fmaxf(acc1.x, 0.f); acc1.y = fmaxf(acc1.y, 0.f);
    acc1.z = fmaxf(acc1.z, 0.f); acc1.w = fmaxf(acc1.w, 0.f);
    *(float4*)(h + (size_t)(base + r) * HID + c) = acc0;
    *(float4*)(h + (size_t)(base + r + 16) * HID + c) = acc1;
    __syncthreads();
    float (*H2)[68] = (float(*)[68])Xs;
    *(float4*)&H2[r][c] = acc0;
    *(float4*)&H2[r + 16][c] = acc1;
    __syncthreads();
    float4 s0v = {0.f,0.f,0.f,0.f}, s1v = {0.f,0.f,0.f,0.f};
    #pragma unroll 8
    for (int k = 0; k < 64; ++k) {
        float a0 = H2[r][k];
        float a1 = H2[r + 16][k];
        float4 b = *(const float4*)&W2[k][c];
        s0v.x += a0 * b.x; s0v.y += a0 * b.y; s0v.z += a0 * b.z; s0v.w += a0 * b.w;
        s1v.x += a1 * b.x; s1v.y += a1 * b.y; s1v.z += a1 * b.z; s1v.w += a1 * b.w;
    }
    uint2 p0, p1;
    p0.x = packbf2(s0v.x, s0v.y); p0.y = packbf2(s0v.z, s0v.w);
    p1.x = packbf2(s1v.x, s1v.y); p1.y = packbf2(s1v.z, s1v.w);
    ((uint2*)hlb)[(size_t)(base + r) * 16 + (c >> 2)] = p0;
    ((uint2*)hlb)[(size_t)(base + r + 16) * 16 + (c >> 2)] = p1;
    float4 A = *(const float4*)(as_w + c);
    float4 D = *(const float4*)(ad_w + c);
    A.x *= LOG2E; A.y *= LOG2E; A.z *= LOG2E; A.w *= LOG2E;
    D.x *= LOG2E; D.y *= LOG2E; D.z *= LOG2E; D.w *= LOG2E;
    float s0 = s0v.x * A.x + s0v.y * A.y + s0v.z * A.z + s0v.w * A.w;
    float d0 = s0v.x * D.x + s0v.y * D.y + s0v.z * D.z + s0v.w * D.w;
    float s1 = s1v.x * A.x + s1v.y * A.y + s1v.z * A.z + s1v.w * A.w;
    float d1 = s1v.x * D.x + s1v.y * D.y + s1v.z * D.z + s1v.w * D.w;
    #pragma unroll
    for (int off = 1; off < 4; off <<= 1) {
        s0 += __shfl_xor(s0, off); d0 += __shfl_xor(d0, off);
        s1 += __shfl_xor(s1, off); d1 += __shfl_xor(d1, off);
    }
    if ((t & 3) == 0) {
        int head = (t & 15) >> 2;
        as_o[(size_t)(base + r) * HEADS + head] = s0;
        ad_o[(size_t)(base + r) * HEADS + head] = d0;
        as_o[(size_t)(base + r + 16) * HEADS + head] = s1;
        ad_o[(size_t)(base + r + 16) * HEADS + head] = d1;
    }
}

// ---- kernel B: hl(bf16) = h @ Wg + per-(node,head) alpha reductions ----
__global__ __launch_bounds__(256) void k_gat_lin(
        const float* __restrict__ h, const float* __restrict__ W,
        const float* __restrict__ as_w, const float* __restrict__ ad_w,
        unsigned* __restrict__ hlb, float* __restrict__ as_o, float* __restrict__ ad_o) {
    __shared__ float Xs[32][68];
    __shared__ float Ws[64][64];
    int t = threadIdx.x;
    const float4* W4 = (const float4*)W;
    float4* Ws4 = (float4*)&Ws[0][0];
    #pragma unroll
    for (int i = 0; i < 4; ++i) Ws4[t + 256 * i] = W4[t + 256 * i];
    int base = blockIdx.x * 32;
    const float4* X4 = (const float4*)(h + (size_t)base * HID);
    #pragma unroll
    for (int i = 0; i < 2; ++i) {
        int f = t + 256 * i;
        int row = f >> 4, col4 = f & 15;
        ((float4*)&Xs[row][0])[col4] = X4[f];
    }
    __syncthreads();
    int r = t >> 4;
    int c = (t & 15) * 4;
    float4 acc0 = {0.f, 0.f, 0.f, 0.f}, acc1 = {0.f, 0.f, 0.f, 0.f};
    #pragma unroll 8
    for (int k = 0; k < 64; ++k) {
        float a0 = Xs[r][k];
        float a1 = Xs[r + 16][k];
        float4 b = *(const float4*)&Ws[k][c];
        acc0.x += a0 * b.x; acc0.y += a0 * b.y; acc0.z += a0 * b.z; acc0.w += a0 * b.w;
        acc1.x += a1 * b.x; acc1.y += a1 * b.y; acc1.z += a1 * b.z; acc1.w += a1 * b.w;
    }
    uint2 p0, p1;
    p0.x = packbf2(acc0.x, acc0.y); p0.y = packbf2(acc0.z, acc0.w);
    p1.x = packbf2(acc1.x, acc1.y); p1.y = packbf2(acc1.z, acc1.w);
    ((uint2*)hlb)[(size_t)(base + r) * 16 + (c >> 2)] = p0;
    ((uint2*)hlb)[(size_t)(base + r + 16) * 16 + (c >> 2)] = p1;
    float4 A = *(const float4*)(as_w + c);
    float4 D = *(const float4*)(ad_w + c);
    A.x *= LOG2E; A.y *= LOG2E; A.z *= LOG2E; A.w *= LOG2E;
    D.x *= LOG2E; D.y *= LOG2E; D.z *= LOG2E; D.w *= LOG2E;
    float s0 = acc0.x * A.x + acc0.y * A.y + acc0.z * A.z + acc0.w * A.w;
    float d0 = acc0.x * D.x + acc0.y * D.y + acc0.z * D.z + acc0.w * D.w;
    float s1 = acc1.x * A.x + acc1.y * A.y + acc1.z * A.z + acc1.w * A.w;
    float d1 = acc1.x * D.x + acc1.y * D.y + acc1.z * D.z + acc1.w * D.w;
    #pragma unroll
    for (int off = 1; off < 4; off <<= 1) {
        s0 += __shfl_xor(s0, off); d0 += __shfl_xor(d0, off);
        s1 += __shfl_xor(s1, off); d1 += __shfl_xor(d1, off);
    }
    if ((t & 3) == 0) {
        int head = (t & 15) >> 2;
        as_o[(size_t)(base + r) * HEADS + head] = s0;
        ad_o[(size_t)(base + r) * HEADS + head] = d0;
        as_o[(size_t)(base + r + 16) * HEADS + head] = s1;
        ad_o[(size_t)(base + r + 16) * HEADS + head] = d1;
    }
}

// ---- CSR build: merged histogram + scan (last-block trick) ----
__global__ __launch_bounds__(256) void k_bhist_scan(
        const int* __restrict__ dstp, int* __restrict__ bcnt,
        int* __restrict__ done, int* __restrict__ bbase, int* __restrict__ bcur) {
    __shared__ int c[NBUCK_PAD];
    __shared__ int tsum[256];
    __shared__ int lastFlag;
    int t = threadIdx.x;
    for (int i = t; i < NBUCK_PAD; i += 256) c[i] = 0;
    __syncthreads();
    for (int i = blockIdx.x * 256 + t; i < E_EDGES; i += gridDim.x * 256)
        atomicAdd(&c[dstp[i] >> BUCK_SHIFT], 1);
    __syncthreads();
    for (int i = t; i < NBUCK_PAD; i += 256) {
        int v = c[i];
        if (v) atomicAdd(bcnt + i, v);
    }
    __threadfence();
    if (t == 0) lastFlag = (atomicAdd(done, 1) == (int)gridDim.x - 1);
    __syncthreads();
    if (!lastFlag) return;
    // last block: exclusive scan of bcnt[1024] with 256 threads x 4 elems
    int v0 = bcnt[t * 4 + 0], v1 = bcnt[t * 4 + 1];
    int v2 = bcnt[t * 4 + 2], v3 = bcnt[t * 4 + 3];
    int local = v0 + v1 + v2 + v3;
    tsum[t] = local;
    __syncthreads();
    for (int off = 1; off < 256; off <<= 1) {
        int u = (t >= off) ? tsum[t - off] : 0;
        __syncthreads();
        tsum[t] += u;
        __syncthreads();
    }
    int p = tsum[t] - local;     // exclusive over threads
    bbase[t * 4 + 0] = p; bcur[t * 4 + 0] = p; p += v0;
    bbase[t * 4 + 1] = p; bcur[t * 4 + 1] = p; p += v1;
    bbase[t * 4 + 2] = p; bcur[t * 4 + 2] = p; p += v2;
    bbase[t * 4 + 3] = p; bcur[t * 4 + 3] = p; p += v3;
    if (t == 255) bbase[NBUCK_PAD] = p;
}

// ebuf element: src (17 bits) | dst_low7 << 17
__global__ __launch_bounds__(256) void k_part(const int* __restrict__ srcp,
                                              const int* __restrict__ dstp,
                                              int* __restrict__ bcur,
                                              unsigned* __restrict__ ebuf) {
    __shared__ int cnt[NBUCK_PAD];
    __shared__ int gbase[NBUCK_PAD];
    int t = threadIdx.x;
    for (int i = t; i < NBUCK_PAD; i += 256) cnt[i] = 0;
    int e0 = blockIdx.x * PART_CHUNK;
    int e1 = min(e0 + PART_CHUNK, E_EDGES);
    __syncthreads();
    for (int i = e0 + t; i < e1; i += 256)
        atomicAdd(&cnt[dstp[i] >> BUCK_SHIFT], 1);
    __syncthreads();
    for (int b = t; b < NBUCK_PAD; b += 256) {
        int c = cnt[b];
        gbase[b] = c ? atomicAdd(bcur + b, c) : 0;
        cnt[b] = 0;
    }
    __syncthreads();
    for (int i = e0 + t; i < e1; i += 256) {
        int d = dstp[i];
        int b = d >> BUCK_SHIFT;
        int pos = gbase[b] + atomicAdd(&cnt[b], 1);
        ebuf[pos] = (unsigned)srcp[i] | ((unsigned)(d & 127) << 17);
    }
}

__global__ __launch_bounds__(256) void k_fin(const int* __restrict__ bbase,
                                             const unsigned* __restrict__ ebuf,
                                             int* __restrict__ row,
                                             int* __restrict__ ssrc) {
    __shared__ int cnt[NODES_PER_BUCK];
    __shared__ int sc[NODES_PER_BUCK];
    __shared__ int rbase[NODES_PER_BUCK];
    int t = threadIdx.x;
    int b = blockIdx.x;
    int start = bbase[b], end = bbase[b + 1];
    int nb0 = b << BUCK_SHIFT;
    if (t < NODES_PER_BUCK) cnt[t] = 0;
    __syncthreads();
    for (int i = start + t; i < end; i += 256)
        atomicAdd(&cnt[ebuf[i] >> 17], 1);
    __syncthreads();
    if (t < NODES_PER_BUCK) sc[t] = cnt[t];
    __syncthreads();
    for (int off = 1; off < NODES_PER_BUCK; off <<= 1) {
        int v = (t < NODES_PER_BUCK && t >= off) ? sc[t - off] : 0;
        __syncthreads();
        if (t < NODES_PER_BUCK) sc[t] += v;
        __syncthreads();
    }
    if (t < NODES_PER_BUCK) {
        int rb = start + sc[t] - cnt[t];
        rbase[t] = rb;
        int n = nb0 + t;
        if (n < N_NODES) row[n] = rb;
        cnt[t] = 0;
    }
    if (b == NBUCK - 1 && t == 0) row[N_NODES] = E_EDGES;
    __syncthreads();
    for (int i = start + t; i < end; i += 256) {
        unsigned p = ebuf[i];
        int l = (int)(p >> 17);
        int slot = rbase[l] + atomicAdd(&cnt[l], 1);
        ssrc[slot] = (int)(p & 0x1FFFFu);
    }
}

// ---- fused aggregation: wave/node, 8 groups x 8 lanes, uint4 loads,
//      packed-f32 accumulate (v_pk_fma_f32), 16 edges in flight ----
__global__ __launch_bounds__(256) void k_gat_agg(
        const int* __restrict__ row, const int* __restrict__ ssrc,
        const float* __restrict__ as_, const float* __restrict__ ad_,
        const unsigned* __restrict__ hlb, const float* __restrict__ hres,
        const float* __restrict__ bg, const float* __restrict__ g,
        const float* __restrict__ b, float* __restrict__ hout,
        const float* __restrict__ Wout, const float* __restrict__ bout,
        float* __restrict__ out, int last) {
    int gid = blockIdx.x * blockDim.x + threadIdx.x;
    int n = gid >> 6;
    if (n >= N_NODES) return;
    int lane = threadIdx.x & 63;
    int grp = lane >> 3;          // 0..7: edge group
    int q   = lane & 7;           // channels 8q..8q+7
    int head = q >> 1;
    const char* hlbc = (const char*)hlb;   // row stride 128 B
    const char* asc  = (const char*)as_;   // row stride 16 B
    unsigned qb = (unsigned)q * 16u;
    unsigned hb = (unsigned)head * 4u;
    float adh = ad_[n * 4 + head];
    f2v acc[4];
    #pragma unroll
    for (int i = 0; i < 4; ++i) { acc[i].x = 0.f; acc[i].y = 0.f; }
    float z = 0.f;
    if (grp == 0) {   // self loop
        float w = lrexp2(*(const float*)(asc + ((unsigned)n * 16u + hb)) + adh);
        f2v w2; w2.x = w; w2.y = w;
        uint4 u = *(const uint4*)(hlbc + ((unsigned)n * 128u + qb));
        acc[0] = w2 * unp2(u.x);
        acc[1] = w2 * unp2(u.y);
        acc[2] = w2 * unp2(u.z);
        acc[3] = w2 * unp2(u.w);
        z = w;
    }
    int j = row[n] + grp;
    int jend = row[n + 1];
    for (; j + 8 < jend; j += 16) {
        unsigned s0 = (unsigned)ssrc[j], s1 = (unsigned)ssrc[j + 8];
        float wa = lrexp2(*(const float*)(asc + (s0 * 16u + hb)) + adh);
        float wb = lrexp2(*(const float*)(asc + (s1 * 16u + hb)) + adh);
        uint4 ua = *(const uint4*)(hlbc + (s0 * 128u + qb));
        uint4 ub = *(const uint4*)(hlbc + (s1 * 128u + qb));
        f2v wa2; wa2.x = wa; wa2.y = wa;
        f2v wb2; wb2.x = wb; wb2.y = wb;
        acc[0] += wa2 * unp2(ua.x); acc[1] += wa2 * unp2(ua.y);
        acc[2] += wa2 * unp2(ua.z); acc[3] += wa2 * unp2(ua.w);
        acc[0] += wb2 * unp2(ub.x); acc[1] += wb2 * unp2(ub.y);
        acc[2] += wb2 * unp2(ub.z); acc[3] += wb2 * unp2(ub.w);
        z += wa + wb;
    }
    if (j < jend) {
        unsigned s0 = (unsigned)ssrc[j];
        float wa = lrexp2(*(const float*)(asc + (s0 * 16u + hb)) + adh);
        uint4 ua = *(const uint4*)(hlbc + (s0 * 128u + qb));
        f2v wa2; wa2.x = wa; wa2.y = wa;
        acc[0] += wa2 * unp2(ua.x); acc[1] += wa2 * unp2(ua.y);
        acc[2] += wa2 * unp2(ua.z); acc[3] += wa2 * unp2(ua.w);
        z += wa;
    }
    // merge the 8 edge-groups (lanes with equal q)
    #pragma unroll
    for (int i = 0; i < 4; ++i) {
        acc[i].x += __shfl_xor(acc[i].x, 8);
        acc[i].y += __shfl_xor(acc[i].y, 8);
        acc[i].x += __shfl_xor(acc[i].x, 16);
        acc[i].y += __shfl_xor(acc[i].y, 16);
        acc[i].x += __shfl_xor(acc[i].x, 32);
        acc[i].y += __shfl_xor(acc[i].y, 32);
    }
    z += __shfl_xor(z, 8); z += __shfl_xor(z, 16); z += __shfl_xor(z, 32);
    float rz = 1.f / (z + 1e-16f);
    float4 bg0 = ((const float4*)bg)[2 * q];
    float4 bg1 = ((const float4*)bg)[2 * q + 1];
    float v[8];
    v[0] = acc[0].x * rz + bg0.x; v[1] = acc[0].y * rz + bg0.y;
    v[2] = acc[1].x * rz + bg0.z; v[3] = acc[1].y * rz + bg0.w;
    v[4] = acc[2].x * rz + bg1.x; v[5] = acc[2].y * rz + bg1.y;
    v[6] = acc[3].x * rz + bg1.z; v[7] = acc[3].y * rz + bg1.w;
    float ssum = 0.f;
    #pragma unroll
    for (int i = 0; i < 8; ++i) ssum += v[i];
    #pragma unroll
    for (int off = 1; off < 8; off <<= 1) ssum += __shfl_xor(ssum, off);
    float mu = ssum * (1.f / 64.f);
    float vs = 0.f;
    #pragma unroll
    for (int i = 0; i < 8; ++i) { v[i] -= mu; vs += v[i] * v[i]; }
    #pragma unroll
    for (int off = 1; off < 8; off <<= 1) vs += __shfl_xor(vs, off);
    float rstd = rsqrtf(vs * (1.f / 64.f) + LN_EPS);
    float4 g0 = ((const float4*)g)[2 * q];
    float4 g1 = ((const float4*)g)[2 * q + 1];
    float4 b0 = ((const float4*)b)[2 * q];
    float4 b1 = ((const float4*)b)[2 * q + 1];
    float4 h0 = ((const float4*)hres)[(size_t)n * 16 + 2 * q];
    float4 h1 = ((const float4*)hres)[(size_t)n * 16 + 2 * q + 1];
    float y[8];
    y[0] = fmaxf(v[0] * rstd * g0.x + b0.x, 0.f) + h0.x;
    y[1] = fmaxf(v[1] * rstd * g0.y + b0.y, 0.f) + h0.y;
    y[2] = fmaxf(v[2] * rstd * g0.z + b0.z, 0.f) + h0.z;
    y[3] = fmaxf(v[3] * rstd * g0.w + b0.w, 0.f) + h0.w;
    y[4] = fmaxf(v[4] * rstd * g1.x + b1.x, 0.f) + h1.x;
    y[5] = fmaxf(v[5] * rstd * g1.y + b1.y, 0.f) + h1.y;
    y[6] = fmaxf(v[6] * rstd * g1.z + b1.z, 0.f) + h1.z;
    y[7] = fmaxf(v[7] * rstd * g1.w + b1.w, 0.f) + h1.w;
    if (!last) {
        if (grp == 0) {
            float4 o0; o0.x = y[0]; o0.y = y[1]; o0.z = y[2]; o0.w = y[3];
            float4 o1; o1.x = y[4]; o1.y = y[5]; o1.z = y[6]; o1.w = y[7];
            ((float4*)hout)[(size_t)n * 16 + 2 * q] = o0;
            ((float4*)hout)[(size_t)n * 16 + 2 * q + 1] = o1;
        }
    } else {
        float4 w0 = ((const float4*)Wout)[2 * q];
        float4 w1 = ((const float4*)Wout)[2 * q + 1];
        float pp = y[0] * w0.x + y[1] * w0.y + y[2] * w0.z + y[3] * w0.w
                 + y[4] * w1.x + y[5] * w1.y + y[6] * w1.z + y[7] * w1.w;
        #pragma unroll
        for (int off = 1; off < 8; off <<= 1) pp += __shfl_xor(pp, off);
        if (lane == 0) out[n] = pp + bout[0];
    }
}

extern "C" void kernel_launch(void* const* d_in, const int* in_sizes, int n_in,
                              void* d_out, int out_size, void* d_ws, size_t ws_size,
                              hipStream_t stream) {
    const float* x     = (const float*)d_in[0];
    const int*   ei    = (const int*)  d_in[1];
    const float* Win   = (const float*)d_in[2];
    const float* bin_  = (const float*)d_in[3];
    const float* Wg    = (const float*)d_in[4];
    const float* att_s = (const float*)d_in[5];
    const float* att_d = (const float*)d_in[6];
    const float* bg    = (const float*)d_in[7];
    const float* lng   = (const float*)d_in[8];
    const float* lnb   = (const float*)d_in[9];
    const float* Wout  = (const float*)d_in[10];
    const float* bout  = (const float*)d_in[11];
    float* out = (float*)d_out;

    float* hA   = (float*)d_ws;                        // h (layer input / residual)
    float* hC   = hA + (size_t)N_NODES * 64;           // h (layer output)
    unsigned* hlb = (unsigned*)(hC + (size_t)N_NODES * 64);  // bf16x2 [N][32]
    float* as_  = (float*)(hlb + (size_t)N_NODES * 32);
    float* ad_  = as_ + (size_t)N_NODES * 4;
    int* row    = (int*)(ad_ + (size_t)N_NODES * 4);   // N+1
    int* bcnt   = row + (N_NODES + 1);                 // 1024
    int* done   = bcnt + NBUCK_PAD;                    // 1
    int* bbase  = done + 1;                            // 1025
    int* bcur   = bbase + (NBUCK_PAD + 1);             // 1024
    int* ssrc   = bcur + NBUCK_PAD;                    // E
    unsigned* ebuf = (unsigned*)(ssrc + E_EDGES);      // E packed

    const int* srcp = ei;
    const int* dstp = ei + E_EDGES;

    hipMemsetAsync(bcnt, 0, (NBUCK_PAD + 1) * sizeof(int), stream);   // bcnt + done
    k_bhist_scan<<<HIST_BLOCKS, 256, 0, stream>>>(dstp, bcnt, done, bbase, bcur);
    k_part<<<(E_EDGES + PART_CHUNK - 1) / PART_CHUNK, 256, 0, stream>>>(srcp, dstp, bcur, ebuf);
    k_fin<<<NBUCK, 256, 0, stream>>>(bbase, ebuf, row, ssrc);

    k_in_proj_fused<<<N_NODES / 32, 256, 0, stream>>>(
        x, Win, bin_, Wg, att_s, att_d, hA, hlb, as_, ad_);

    const int aggBlocks = (N_NODES * 64 + 255) / 256;
    for (int L = 0; L < 3; ++L) {
        if (L > 0) {
            k_gat_lin<<<N_NODES / 32, 256, 0, stream>>>(hA, Wg + L * 64 * 64,
                                                att_s + L * 64, att_d + L * 64,
                                                hlb, as_, ad_);
        }
        k_gat_agg<<<aggBlocks, 256, 0, stream>>>(row, ssrc, as_, ad_, hlb, hA,
                                                 bg + L * 64, lng + L * 64, lnb + L * 64,
                                                 hC, Wout, bout, out, (L == 2) ? 1 : 0);
        float* t = hA; hA = hC; hC = t;
    }
}

// Round 10
// 316.239 us; speedup vs baseline: 1.1167x; 1.1167x over previous
//
#include <hip/hip_runtime.h>
#include <hip/hip_bf16.h>

#define N_NODES 100000
#define E_EDGES 1600000
#define IN_DIM  128
#define HID     64
#define HEADS   4
#define NEG_SLOPE 0.2f
#define LN_EPS  1e-5f
#define LOG2E   1.4426950408889634f

#define BUCK_SHIFT 7
#define NODES_PER_BUCK 128
#define NBUCK ((N_NODES + NODES_PER_BUCK - 1) / NODES_PER_BUCK)   // 782
#define NBUCK_PAD 1024
#define PART_CHUNK 8192
#define HIST_BLOCKS 256

typedef float f2v __attribute__((ext_vector_type(2)));

__device__ __forceinline__ f2v unp2(unsigned u) {
    f2v r; r.x = __uint_as_float(u << 16); r.y = __uint_as_float(u & 0xffff0000u); return r;
}
__device__ __forceinline__ unsigned packbf2(float a, float b) {
    unsigned ua = __float_as_uint(a), ub = __float_as_uint(b);
    ua += 0x7fffu + ((ua >> 16) & 1u);
    ub += 0x7fffu + ((ub >> 16) & 1u);
    return (ua >> 16) | (ub & 0xffff0000u);
}
// e pre-scaled by LOG2E; weight = exp(lrelu(e_orig)) = 2^(lrelu(e))
__device__ __forceinline__ float lrexp2(float e) {
    return __builtin_amdgcn_exp2f(fmaxf(e, NEG_SLOPE * e));
}

// ---- fused: h0 = relu(x @ Win + bin); hl0(bf16) = h0 @ Wg0; alpha0 ----
__global__ __launch_bounds__(256) void k_in_proj_fused(
        const float* __restrict__ x, const float* __restrict__ W,
        const float* __restrict__ bias,
        const float* __restrict__ W2g, const float* __restrict__ as_w,
        const float* __restrict__ ad_w,
        float* __restrict__ h, unsigned* __restrict__ hlb,
        float* __restrict__ as_o, float* __restrict__ ad_o) {
    __shared__ float Xs[32][132];     // reused as H2[32][68] later
    __shared__ float Ws[128][64];
    __shared__ float W2[64][64];
    int t = threadIdx.x;
    const float4* W4 = (const float4*)W;
    float4* Ws4 = (float4*)&Ws[0][0];
    #pragma unroll
    for (int i = 0; i < 8; ++i) Ws4[t + 256 * i] = W4[t + 256 * i];
    const float4* W24 = (const float4*)W2g;
    float4* W2s4 = (float4*)&W2[0][0];
    #pragma unroll
    for (int i = 0; i < 4; ++i) W2s4[t + 256 * i] = W24[t + 256 * i];
    int base = blockIdx.x * 32;
    const float4* X4 = (const float4*)(x + (size_t)base * IN_DIM);
    #pragma unroll
    for (int i = 0; i < 4; ++i) {
        int f = t + 256 * i;
        int row = f >> 5, col4 = f & 31;
        ((float4*)&Xs[row][0])[col4] = X4[f];
    }
    __syncthreads();
    int r = t >> 4;
    int c = (t & 15) * 4;
    float4 bb = *(const float4*)(bias + c);
    float4 acc0 = bb, acc1 = bb;
    #pragma unroll 8
    for (int k = 0; k < 128; ++k) {
        float a0 = Xs[r][k];
        float a1 = Xs[r + 16][k];
        float4 b = *(const float4*)&Ws[k][c];
        acc0.x += a0 * b.x; acc0.y += a0 * b.y; acc0.z += a0 * b.z; acc0.w += a0 * b.w;
        acc1.x += a1 * b.x; acc1.y += a1 * b.y; acc1.z += a1 * b.z; acc1.w += a1 * b.w;
    }
    acc0.x = fmaxf(acc0.x, 0.f); acc0.y = fmaxf(acc0.y, 0.f);
    acc0.z = fmaxf(acc0.z, 0.f); acc0.w = fmaxf(acc0.w, 0.f);
    acc1.x = fmaxf(acc1.x, 0.f); acc1.y = fmaxf(acc1.y, 0.f);
    acc1.z = fmaxf(acc1.z, 0.f); acc1.w = fmaxf(acc1.w, 0.f);
    *(float4*)(h + (size_t)(base + r) * HID + c) = acc0;
    *(float4*)(h + (size_t)(base + r + 16) * HID + c) = acc1;
    __syncthreads();
    float (*H2)[68] = (float(*)[68])Xs;
    *(float4*)&H2[r][c] = acc0;
    *(float4*)&H2[r + 16][c] = acc1;
    __syncthreads();
    float4 s0v = {0.f,0.f,0.f,0.f}, s1v = {0.f,0.f,0.f,0.f};
    #pragma unroll 8
    for (int k = 0; k < 64; ++k) {
        float a0 = H2[r][k];
        float a1 = H2[r + 16][k];
        float4 b = *(const float4*)&W2[k][c];
        s0v.x += a0 * b.x; s0v.y += a0 * b.y; s0v.z += a0 * b.z; s0v.w += a0 * b.w;
        s1v.x += a1 * b.x; s1v.y += a1 * b.y; s1v.z += a1 * b.z; s1v.w += a1 * b.w;
    }
    uint2 p0, p1;
    p0.x = packbf2(s0v.x, s0v.y); p0.y = packbf2(s0v.z, s0v.w);
    p1.x = packbf2(s1v.x, s1v.y); p1.y = packbf2(s1v.z, s1v.w);
    ((uint2*)hlb)[(size_t)(base + r) * 16 + (c >> 2)] = p0;
    ((uint2*)hlb)[(size_t)(base + r + 16) * 16 + (c >> 2)] = p1;
    float4 A = *(const float4*)(as_w + c);
    float4 D = *(const float4*)(ad_w + c);
    A.x *= LOG2E; A.y *= LOG2E; A.z *= LOG2E; A.w *= LOG2E;
    D.x *= LOG2E; D.y *= LOG2E; D.z *= LOG2E; D.w *= LOG2E;
    float s0 = s0v.x * A.x + s0v.y * A.y + s0v.z * A.z + s0v.w * A.w;
    float d0 = s0v.x * D.x + s0v.y * D.y + s0v.z * D.z + s0v.w * D.w;
    float s1 = s1v.x * A.x + s1v.y * A.y + s1v.z * A.z + s1v.w * A.w;
    float d1 = s1v.x * D.x + s1v.y * D.y + s1v.z * D.z + s1v.w * D.w;
    #pragma unroll
    for (int off = 1; off < 4; off <<= 1) {
        s0 += __shfl_xor(s0, off); d0 += __shfl_xor(d0, off);
        s1 += __shfl_xor(s1, off); d1 += __shfl_xor(d1, off);
    }
    if ((t & 3) == 0) {
        int head = (t & 15) >> 2;
        as_o[(size_t)(base + r) * HEADS + head] = s0;
        ad_o[(size_t)(base + r) * HEADS + head] = d0;
        as_o[(size_t)(base + r + 16) * HEADS + head] = s1;
        ad_o[(size_t)(base + r + 16) * HEADS + head] = d1;
    }
}

// ---- kernel B: hl(bf16) = h @ Wg + per-(node,head) alpha reductions ----
__global__ __launch_bounds__(256) void k_gat_lin(
        const float* __restrict__ h, const float* __restrict__ W,
        const float* __restrict__ as_w, const float* __restrict__ ad_w,
        unsigned* __restrict__ hlb, float* __restrict__ as_o, float* __restrict__ ad_o) {
    __shared__ float Xs[32][68];
    __shared__ float Ws[64][64];
    int t = threadIdx.x;
    const float4* W4 = (const float4*)W;
    float4* Ws4 = (float4*)&Ws[0][0];
    #pragma unroll
    for (int i = 0; i < 4; ++i) Ws4[t + 256 * i] = W4[t + 256 * i];
    int base = blockIdx.x * 32;
    const float4* X4 = (const float4*)(h + (size_t)base * HID);
    #pragma unroll
    for (int i = 0; i < 2; ++i) {
        int f = t + 256 * i;
        int row = f >> 4, col4 = f & 15;
        ((float4*)&Xs[row][0])[col4] = X4[f];
    }
    __syncthreads();
    int r = t >> 4;
    int c = (t & 15) * 4;
    float4 acc0 = {0.f, 0.f, 0.f, 0.f}, acc1 = {0.f, 0.f, 0.f, 0.f};
    #pragma unroll 8
    for (int k = 0; k < 64; ++k) {
        float a0 = Xs[r][k];
        float a1 = Xs[r + 16][k];
        float4 b = *(const float4*)&Ws[k][c];
        acc0.x += a0 * b.x; acc0.y += a0 * b.y; acc0.z += a0 * b.z; acc0.w += a0 * b.w;
        acc1.x += a1 * b.x; acc1.y += a1 * b.y; acc1.z += a1 * b.z; acc1.w += a1 * b.w;
    }
    uint2 p0, p1;
    p0.x = packbf2(acc0.x, acc0.y); p0.y = packbf2(acc0.z, acc0.w);
    p1.x = packbf2(acc1.x, acc1.y); p1.y = packbf2(acc1.z, acc1.w);
    ((uint2*)hlb)[(size_t)(base + r) * 16 + (c >> 2)] = p0;
    ((uint2*)hlb)[(size_t)(base + r + 16) * 16 + (c >> 2)] = p1;
    float4 A = *(const float4*)(as_w + c);
    float4 D = *(const float4*)(ad_w + c);
    A.x *= LOG2E; A.y *= LOG2E; A.z *= LOG2E; A.w *= LOG2E;
    D.x *= LOG2E; D.y *= LOG2E; D.z *= LOG2E; D.w *= LOG2E;
    float s0 = acc0.x * A.x + acc0.y * A.y + acc0.z * A.z + acc0.w * A.w;
    float d0 = acc0.x * D.x + acc0.y * D.y + acc0.z * D.z + acc0.w * D.w;
    float s1 = acc1.x * A.x + acc1.y * A.y + acc1.z * A.z + acc1.w * A.w;
    float d1 = acc1.x * D.x + acc1.y * D.y + acc1.z * D.z + acc1.w * D.w;
    #pragma unroll
    for (int off = 1; off < 4; off <<= 1) {
        s0 += __shfl_xor(s0, off); d0 += __shfl_xor(d0, off);
        s1 += __shfl_xor(s1, off); d1 += __shfl_xor(d1, off);
    }
    if ((t & 3) == 0) {
        int head = (t & 15) >> 2;
        as_o[(size_t)(base + r) * HEADS + head] = s0;
        ad_o[(size_t)(base + r) * HEADS + head] = d0;
        as_o[(size_t)(base + r + 16) * HEADS + head] = s1;
        ad_o[(size_t)(base + r + 16) * HEADS + head] = d1;
    }
}

// ---- CSR build: merged histogram + scan (last-block trick) ----
__global__ __launch_bounds__(256) void k_bhist_scan(
        const int* __restrict__ dstp, int* __restrict__ bcnt,
        int* __restrict__ done, int* __restrict__ bbase, int* __restrict__ bcur) {
    __shared__ int c[NBUCK_PAD];
    __shared__ int tsum[256];
    __shared__ int lastFlag;
    int t = threadIdx.x;
    for (int i = t; i < NBUCK_PAD; i += 256) c[i] = 0;
    __syncthreads();
    for (int i = blockIdx.x * 256 + t; i < E_EDGES; i += gridDim.x * 256)
        atomicAdd(&c[dstp[i] >> BUCK_SHIFT], 1);
    __syncthreads();
    for (int i = t; i < NBUCK_PAD; i += 256) {
        int v = c[i];
        if (v) atomicAdd(bcnt + i, v);
    }
    __threadfence();
    if (t == 0) lastFlag = (atomicAdd(done, 1) == (int)gridDim.x - 1);
    __syncthreads();
    if (!lastFlag) return;
    int v0 = bcnt[t * 4 + 0], v1 = bcnt[t * 4 + 1];
    int v2 = bcnt[t * 4 + 2], v3 = bcnt[t * 4 + 3];
    int local = v0 + v1 + v2 + v3;
    tsum[t] = local;
    __syncthreads();
    for (int off = 1; off < 256; off <<= 1) {
        int u = (t >= off) ? tsum[t - off] : 0;
        __syncthreads();
        tsum[t] += u;
        __syncthreads();
    }
    int p = tsum[t] - local;     // exclusive over threads
    bbase[t * 4 + 0] = p; bcur[t * 4 + 0] = p; p += v0;
    bbase[t * 4 + 1] = p; bcur[t * 4 + 1] = p; p += v1;
    bbase[t * 4 + 2] = p; bcur[t * 4 + 2] = p; p += v2;
    bbase[t * 4 + 3] = p; bcur[t * 4 + 3] = p; p += v3;
    if (t == 255) bbase[NBUCK_PAD] = p;
}

// ebuf element: src (17 bits) | dst_low7 << 17
__global__ __launch_bounds__(256) void k_part(const int* __restrict__ srcp,
                                              const int* __restrict__ dstp,
                                              int* __restrict__ bcur,
                                              unsigned* __restrict__ ebuf) {
    __shared__ int cnt[NBUCK_PAD];
    __shared__ int gbase[NBUCK_PAD];
    int t = threadIdx.x;
    for (int i = t; i < NBUCK_PAD; i += 256) cnt[i] = 0;
    int e0 = blockIdx.x * PART_CHUNK;
    int e1 = min(e0 + PART_CHUNK, E_EDGES);
    __syncthreads();
    for (int i = e0 + t; i < e1; i += 256)
        atomicAdd(&cnt[dstp[i] >> BUCK_SHIFT], 1);
    __syncthreads();
    for (int b = t; b < NBUCK_PAD; b += 256) {
        int c = cnt[b];
        gbase[b] = c ? atomicAdd(bcur + b, c) : 0;
        cnt[b] = 0;
    }
    __syncthreads();
    for (int i = e0 + t; i < e1; i += 256) {
        int d = dstp[i];
        int b = d >> BUCK_SHIFT;
        int pos = gbase[b] + atomicAdd(&cnt[b], 1);
        ebuf[pos] = (unsigned)srcp[i] | ((unsigned)(d & 127) << 17);
    }
}

__global__ __launch_bounds__(256) void k_fin(const int* __restrict__ bbase,
                                             const unsigned* __restrict__ ebuf,
                                             int* __restrict__ row,
                                             int* __restrict__ ssrc) {
    __shared__ int cnt[NODES_PER_BUCK];
    __shared__ int sc[NODES_PER_BUCK];
    __shared__ int rbase[NODES_PER_BUCK];
    int t = threadIdx.x;
    int b = blockIdx.x;
    int start = bbase[b], end = bbase[b + 1];
    int nb0 = b << BUCK_SHIFT;
    if (t < NODES_PER_BUCK) cnt[t] = 0;
    __syncthreads();
    for (int i = start + t; i < end; i += 256)
        atomicAdd(&cnt[ebuf[i] >> 17], 1);
    __syncthreads();
    if (t < NODES_PER_BUCK) sc[t] = cnt[t];
    __syncthreads();
    for (int off = 1; off < NODES_PER_BUCK; off <<= 1) {
        int v = (t < NODES_PER_BUCK && t >= off) ? sc[t - off] : 0;
        __syncthreads();
        if (t < NODES_PER_BUCK) sc[t] += v;
        __syncthreads();
    }
    if (t < NODES_PER_BUCK) {
        int rb = start + sc[t] - cnt[t];
        rbase[t] = rb;
        int n = nb0 + t;
        if (n < N_NODES) row[n] = rb;
        cnt[t] = 0;
    }
    if (b == NBUCK - 1 && t == 0) row[N_NODES] = E_EDGES;
    __syncthreads();
    for (int i = start + t; i < end; i += 256) {
        unsigned p = ebuf[i];
        int l = (int)(p >> 17);
        int slot = rbase[l] + atomicAdd(&cnt[l], 1);
        ssrc[slot] = (int)(p & 0x1FFFFu);
    }
}

// ---- fused aggregation: 8 nodes per wave, 8 lanes per node.
//      Each group walks its node's edges serially (unroll2, 16 loads in
//      flight per wave). No cross-group merges; LN reduces over 8 lanes. ----
__global__ __launch_bounds__(256) void k_gat_agg(
        const int* __restrict__ row, const int* __restrict__ ssrc,
        const float* __restrict__ as_, const float* __restrict__ ad_,
        const unsigned* __restrict__ hlb, const float* __restrict__ hres,
        const float* __restrict__ bg, const float* __restrict__ g,
        const float* __restrict__ b, float* __restrict__ hout,
        const float* __restrict__ Wout, const float* __restrict__ bout,
        float* __restrict__ out, int last) {
    int gid = blockIdx.x * blockDim.x + threadIdx.x;
    int lane = threadIdx.x & 63;
    int grp = lane >> 3;          // 0..7: node within wave
    int q   = lane & 7;           // channels 8q..8q+7
    int n = (gid >> 6) * 8 + grp;
    if (n >= N_NODES) return;
    int head = q >> 1;
    const char* hlbc = (const char*)hlb;   // row stride 128 B
    const char* asc  = (const char*)as_;   // row stride 16 B
    unsigned nb = (unsigned)n;
    unsigned qb = (unsigned)q * 16u;
    unsigned hb = (unsigned)head * 4u;
    float adh = *(const float*)((const char*)ad_ + (nb * 16u + hb));
    // self loop
    float w = lrexp2(*(const float*)(asc + (nb * 16u + hb)) + adh);
    f2v w2; w2.x = w; w2.y = w;
    uint4 u = *(const uint4*)(hlbc + (nb * 128u + qb));
    f2v acc0 = w2 * unp2(u.x);
    f2v acc1 = w2 * unp2(u.y);
    f2v acc2 = w2 * unp2(u.z);
    f2v acc3 = w2 * unp2(u.w);
    float z = w;
    int j = row[n];
    int jend = row[n + 1];
    for (; j + 1 < jend; j += 2) {
        unsigned s0 = (unsigned)ssrc[j], s1 = (unsigned)ssrc[j + 1];
        float wa = lrexp2(*(const float*)(asc + (s0 * 16u + hb)) + adh);
        float wb = lrexp2(*(const float*)(asc + (s1 * 16u + hb)) + adh);
        uint4 ua = *(const uint4*)(hlbc + (s0 * 128u + qb));
        uint4 ub = *(const uint4*)(hlbc + (s1 * 128u + qb));
        f2v wa2; wa2.x = wa; wa2.y = wa;
        f2v wb2; wb2.x = wb; wb2.y = wb;
        acc0 += wa2 * unp2(ua.x); acc1 += wa2 * unp2(ua.y);
        acc2 += wa2 * unp2(ua.z); acc3 += wa2 * unp2(ua.w);
        acc0 += wb2 * unp2(ub.x); acc1 += wb2 * unp2(ub.y);
        acc2 += wb2 * unp2(ub.z); acc3 += wb2 * unp2(ub.w);
        z += wa + wb;
    }
    if (j < jend) {
        unsigned s0 = (unsigned)ssrc[j];
        float wa = lrexp2(*(const float*)(asc + (s0 * 16u + hb)) + adh);
        uint4 ua = *(const uint4*)(hlbc + (s0 * 128u + qb));
        f2v wa2; wa2.x = wa; wa2.y = wa;
        acc0 += wa2 * unp2(ua.x); acc1 += wa2 * unp2(ua.y);
        acc2 += wa2 * unp2(ua.z); acc3 += wa2 * unp2(ua.w);
        z += wa;
    }
    float rz = 1.f / (z + 1e-16f);
    float4 bg0 = ((const float4*)bg)[2 * q];
    float4 bg1 = ((const float4*)bg)[2 * q + 1];
    float v[8];
    v[0] = acc0.x * rz + bg0.x; v[1] = acc0.y * rz + bg0.y;
    v[2] = acc1.x * rz + bg0.z; v[3] = acc1.y * rz + bg0.w;
    v[4] = acc2.x * rz + bg1.x; v[5] = acc2.y * rz + bg1.y;
    v[6] = acc3.x * rz + bg1.z; v[7] = acc3.y * rz + bg1.w;
    float ssum = 0.f;
    #pragma unroll
    for (int i = 0; i < 8; ++i) ssum += v[i];
    #pragma unroll
    for (int off = 1; off < 8; off <<= 1) ssum += __shfl_xor(ssum, off);
    float mu = ssum * (1.f / 64.f);
    float vs = 0.f;
    #pragma unroll
    for (int i = 0; i < 8; ++i) { v[i] -= mu; vs += v[i] * v[i]; }
    #pragma unroll
    for (int off = 1; off < 8; off <<= 1) vs += __shfl_xor(vs, off);
    float rstd = rsqrtf(vs * (1.f / 64.f) + LN_EPS);
    float4 g0 = ((const float4*)g)[2 * q];
    float4 g1 = ((const float4*)g)[2 * q + 1];
    float4 b0 = ((const float4*)b)[2 * q];
    float4 b1 = ((const float4*)b)[2 * q + 1];
    float4 h0 = ((const float4*)hres)[(size_t)n * 16 + 2 * q];
    float4 h1 = ((const float4*)hres)[(size_t)n * 16 + 2 * q + 1];
    float y[8];
    y[0] = fmaxf(v[0] * rstd * g0.x + b0.x, 0.f) + h0.x;
    y[1] = fmaxf(v[1] * rstd * g0.y + b0.y, 0.f) + h0.y;
    y[2] = fmaxf(v[2] * rstd * g0.z + b0.z, 0.f) + h0.z;
    y[3] = fmaxf(v[3] * rstd * g0.w + b0.w, 0.f) + h0.w;
    y[4] = fmaxf(v[4] * rstd * g1.x + b1.x, 0.f) + h1.x;
    y[5] = fmaxf(v[5] * rstd * g1.y + b1.y, 0.f) + h1.y;
    y[6] = fmaxf(v[6] * rstd * g1.z + b1.z, 0.f) + h1.z;
    y[7] = fmaxf(v[7] * rstd * g1.w + b1.w, 0.f) + h1.w;
    if (!last) {
        float4 o0; o0.x = y[0]; o0.y = y[1]; o0.z = y[2]; o0.w = y[3];
        float4 o1; o1.x = y[4]; o1.y = y[5]; o1.z = y[6]; o1.w = y[7];
        ((float4*)hout)[(size_t)n * 16 + 2 * q] = o0;
        ((float4*)hout)[(size_t)n * 16 + 2 * q + 1] = o1;
    } else {
        float4 w0 = ((const float4*)Wout)[2 * q];
        float4 w1 = ((const float4*)Wout)[2 * q + 1];
        float pp = y[0] * w0.x + y[1] * w0.y + y[2] * w0.z + y[3] * w0.w
                 + y[4] * w1.x + y[5] * w1.y + y[6] * w1.z + y[7] * w1.w;
        #pragma unroll
        for (int off = 1; off < 8; off <<= 1) pp += __shfl_xor(pp, off);
        if (q == 0) out[n] = pp + bout[0];
    }
}

extern "C" void kernel_launch(void* const* d_in, const int* in_sizes, int n_in,
                              void* d_out, int out_size, void* d_ws, size_t ws_size,
                              hipStream_t stream) {
    const float* x     = (const float*)d_in[0];
    const int*   ei    = (const int*)  d_in[1];
    const float* Win   = (const float*)d_in[2];
    const float* bin_  = (const float*)d_in[3];
    const float* Wg    = (const float*)d_in[4];
    const float* att_s = (const float*)d_in[5];
    const float* att_d = (const float*)d_in[6];
    const float* bg    = (const float*)d_in[7];
    const float* lng   = (const float*)d_in[8];
    const float* lnb   = (const float*)d_in[9];
    const float* Wout  = (const float*)d_in[10];
    const float* bout  = (const float*)d_in[11];
    float* out = (float*)d_out;

    float* hA   = (float*)d_ws;                        // h (layer input / residual)
    float* hC   = hA + (size_t)N_NODES * 64;           // h (layer output)
    unsigned* hlb = (unsigned*)(hC + (size_t)N_NODES * 64);  // bf16x2 [N][32]
    float* as_  = (float*)(hlb + (size_t)N_NODES * 32);
    float* ad_  = as_ + (size_t)N_NODES * 4;
    int* row    = (int*)(ad_ + (size_t)N_NODES * 4);   // N+1
    int* bcnt   = row + (N_NODES + 1);                 // 1024
    int* done   = bcnt + NBUCK_PAD;                    // 1
    int* bbase  = done + 1;                            // 1025
    int* bcur   = bbase + (NBUCK_PAD + 1);             // 1024
    int* ssrc   = bcur + NBUCK_PAD;                    // E
    unsigned* ebuf = (unsigned*)(ssrc + E_EDGES);      // E packed

    const int* srcp = ei;
    const int* dstp = ei + E_EDGES;

    hipMemsetAsync(bcnt, 0, (NBUCK_PAD + 1) * sizeof(int), stream);   // bcnt + done
    k_bhist_scan<<<HIST_BLOCKS, 256, 0, stream>>>(dstp, bcnt, done, bbase, bcur);
    k_part<<<(E_EDGES + PART_CHUNK - 1) / PART_CHUNK, 256, 0, stream>>>(srcp, dstp, bcur, ebuf);
    k_fin<<<NBUCK, 256, 0, stream>>>(bbase, ebuf, row, ssrc);

    k_in_proj_fused<<<N_NODES / 32, 256, 0, stream>>>(
        x, Win, bin_, Wg, att_s, att_d, hA, hlb, as_, ad_);

    const int aggBlocks = (N_NODES + 31) / 32;   // 8 nodes/wave, 4 waves/block
    for (int L = 0; L < 3; ++L) {
        if (L > 0) {
            k_gat_lin<<<N_NODES / 32, 256, 0, stream>>>(hA, Wg + L * 64 * 64,
                                                att_s + L * 64, att_d + L * 64,
                                                hlb, as_, ad_);
        }
        k_gat_agg<<<aggBlocks, 256, 0, stream>>>(row, ssrc, as_, ad_, hlb, hA,
                                                 bg + L * 64, lng + L * 64, lnb + L * 64,
                                                 hC, Wout, bout, out, (L == 2) ? 1 : 0);
        float* t = hA; hA = hC; hC = t;
    }
}

// Round 11
// 315.504 us; speedup vs baseline: 1.1193x; 1.0023x over previous
//
#include <hip/hip_runtime.h>
#include <hip/hip_bf16.h>

#define N_NODES 100000
#define E_EDGES 1600000
#define IN_DIM  128
#define HID     64
#define HEADS   4
#define NEG_SLOPE 0.2f
#define LN_EPS  1e-5f
#define LOG2E   1.4426950408889634f

#define BUCK_SHIFT 7
#define NODES_PER_BUCK 128
#define NBUCK ((N_NODES + NODES_PER_BUCK - 1) / NODES_PER_BUCK)   // 782
#define NBUCK_PAD 1024
#define PART_CHUNK 8192
#define HIST_BLOCKS 256

typedef float f2v __attribute__((ext_vector_type(2)));

__device__ __forceinline__ f2v unp2(unsigned u) {
    f2v r; r.x = __uint_as_float(u << 16); r.y = __uint_as_float(u & 0xffff0000u); return r;
}
__device__ __forceinline__ unsigned packbf2(float a, float b) {
    unsigned ua = __float_as_uint(a), ub = __float_as_uint(b);
    ua += 0x7fffu + ((ua >> 16) & 1u);
    ub += 0x7fffu + ((ub >> 16) & 1u);
    return (ua >> 16) | (ub & 0xffff0000u);
}
// e pre-scaled by LOG2E; weight = exp(lrelu(e_orig)) = 2^(lrelu(e))
__device__ __forceinline__ float lrexp2(float e) {
    return __builtin_amdgcn_exp2f(fmaxf(e, NEG_SLOPE * e));
}

// ---- kernel A: h0 = relu(x @ Win + bin). Tiled GEMM, 32 nodes/block.
//      K-chunked weight staging: 33 KB LDS -> 4 blocks/CU. ----
__global__ __launch_bounds__(256) void k_in_proj(
        const float* __restrict__ x, const float* __restrict__ W,
        const float* __restrict__ bias, float* __restrict__ h) {
    __shared__ float Xs[32][132];     // 16.9 KB
    __shared__ float Ws[64][64];      // 16 KB (double-pass)
    int t = threadIdx.x;
    int base = blockIdx.x * 32;
    const float4* X4 = (const float4*)(x + (size_t)base * IN_DIM);
    #pragma unroll
    for (int i = 0; i < 4; ++i) {
        int f = t + 256 * i;
        ((float4*)&Xs[f >> 5][0])[f & 31] = X4[f];
    }
    const float4* W4 = (const float4*)W;
    float4* Ws4 = (float4*)&Ws[0][0];
    #pragma unroll
    for (int i = 0; i < 4; ++i) Ws4[t + 256 * i] = W4[t + 256 * i];
    __syncthreads();
    int r = t >> 4;               // rows {r, r+16}
    int c = (t & 15) * 4;         // cols c..c+3
    float4 bb = *(const float4*)(bias + c);
    float4 acc0 = bb, acc1 = bb;
    #pragma unroll 8
    for (int k = 0; k < 64; ++k) {
        float a0 = Xs[r][k];
        float a1 = Xs[r + 16][k];
        float4 b = *(const float4*)&Ws[k][c];
        acc0.x += a0 * b.x; acc0.y += a0 * b.y; acc0.z += a0 * b.z; acc0.w += a0 * b.w;
        acc1.x += a1 * b.x; acc1.y += a1 * b.y; acc1.z += a1 * b.z; acc1.w += a1 * b.w;
    }
    __syncthreads();   // all reads of Ws chunk 0 done
    #pragma unroll
    for (int i = 0; i < 4; ++i) Ws4[t + 256 * i] = W4[1024 + t + 256 * i];
    __syncthreads();
    #pragma unroll 8
    for (int k = 0; k < 64; ++k) {
        float a0 = Xs[r][64 + k];
        float a1 = Xs[r + 16][64 + k];
        float4 b = *(const float4*)&Ws[k][c];
        acc0.x += a0 * b.x; acc0.y += a0 * b.y; acc0.z += a0 * b.z; acc0.w += a0 * b.w;
        acc1.x += a1 * b.x; acc1.y += a1 * b.y; acc1.z += a1 * b.z; acc1.w += a1 * b.w;
    }
    acc0.x = fmaxf(acc0.x, 0.f); acc0.y = fmaxf(acc0.y, 0.f);
    acc0.z = fmaxf(acc0.z, 0.f); acc0.w = fmaxf(acc0.w, 0.f);
    acc1.x = fmaxf(acc1.x, 0.f); acc1.y = fmaxf(acc1.y, 0.f);
    acc1.z = fmaxf(acc1.z, 0.f); acc1.w = fmaxf(acc1.w, 0.f);
    *(float4*)(h + (size_t)(base + r) * HID + c) = acc0;
    *(float4*)(h + (size_t)(base + r + 16) * HID + c) = acc1;
}

// ---- kernel B: hl(bf16) = h @ Wg + per-(node,head) alpha reductions ----
__global__ __launch_bounds__(256) void k_gat_lin(
        const float* __restrict__ h, const float* __restrict__ W,
        const float* __restrict__ as_w, const float* __restrict__ ad_w,
        unsigned* __restrict__ hlb, float* __restrict__ as_o, float* __restrict__ ad_o) {
    __shared__ float Xs[32][68];
    __shared__ float Ws[64][64];
    int t = threadIdx.x;
    const float4* W4 = (const float4*)W;
    float4* Ws4 = (float4*)&Ws[0][0];
    #pragma unroll
    for (int i = 0; i < 4; ++i) Ws4[t + 256 * i] = W4[t + 256 * i];
    int base = blockIdx.x * 32;
    const float4* X4 = (const float4*)(h + (size_t)base * HID);
    #pragma unroll
    for (int i = 0; i < 2; ++i) {
        int f = t + 256 * i;
        ((float4*)&Xs[f >> 4][0])[f & 15] = X4[f];
    }
    __syncthreads();
    int r = t >> 4;
    int c = (t & 15) * 4;
    float4 acc0 = {0.f, 0.f, 0.f, 0.f}, acc1 = {0.f, 0.f, 0.f, 0.f};
    #pragma unroll 8
    for (int k = 0; k < 64; ++k) {
        float a0 = Xs[r][k];
        float a1 = Xs[r + 16][k];
        float4 b = *(const float4*)&Ws[k][c];
        acc0.x += a0 * b.x; acc0.y += a0 * b.y; acc0.z += a0 * b.z; acc0.w += a0 * b.w;
        acc1.x += a1 * b.x; acc1.y += a1 * b.y; acc1.z += a1 * b.z; acc1.w += a1 * b.w;
    }
    uint2 p0, p1;
    p0.x = packbf2(acc0.x, acc0.y); p0.y = packbf2(acc0.z, acc0.w);
    p1.x = packbf2(acc1.x, acc1.y); p1.y = packbf2(acc1.z, acc1.w);
    ((uint2*)hlb)[(size_t)(base + r) * 16 + (c >> 2)] = p0;
    ((uint2*)hlb)[(size_t)(base + r + 16) * 16 + (c >> 2)] = p1;
    float4 A = *(const float4*)(as_w + c);
    float4 D = *(const float4*)(ad_w + c);
    A.x *= LOG2E; A.y *= LOG2E; A.z *= LOG2E; A.w *= LOG2E;
    D.x *= LOG2E; D.y *= LOG2E; D.z *= LOG2E; D.w *= LOG2E;
    float s0 = acc0.x * A.x + acc0.y * A.y + acc0.z * A.z + acc0.w * A.w;
    float d0 = acc0.x * D.x + acc0.y * D.y + acc0.z * D.z + acc0.w * D.w;
    float s1 = acc1.x * A.x + acc1.y * A.y + acc1.z * A.z + acc1.w * A.w;
    float d1 = acc1.x * D.x + acc1.y * D.y + acc1.z * D.z + acc1.w * D.w;
    #pragma unroll
    for (int off = 1; off < 4; off <<= 1) {
        s0 += __shfl_xor(s0, off); d0 += __shfl_xor(d0, off);
        s1 += __shfl_xor(s1, off); d1 += __shfl_xor(d1, off);
    }
    if ((t & 3) == 0) {
        int head = (t & 15) >> 2;
        as_o[(size_t)(base + r) * HEADS + head] = s0;
        ad_o[(size_t)(base + r) * HEADS + head] = d0;
        as_o[(size_t)(base + r + 16) * HEADS + head] = s1;
        ad_o[(size_t)(base + r + 16) * HEADS + head] = d1;
    }
}

// ---- CSR build: merged histogram + scan (last-block trick) ----
__global__ __launch_bounds__(256) void k_bhist_scan(
        const int* __restrict__ dstp, int* __restrict__ bcnt,
        int* __restrict__ done, int* __restrict__ bbase, int* __restrict__ bcur) {
    __shared__ int c[NBUCK_PAD];
    __shared__ int tsum[256];
    __shared__ int lastFlag;
    int t = threadIdx.x;
    for (int i = t; i < NBUCK_PAD; i += 256) c[i] = 0;
    __syncthreads();
    for (int i = blockIdx.x * 256 + t; i < E_EDGES; i += gridDim.x * 256)
        atomicAdd(&c[dstp[i] >> BUCK_SHIFT], 1);
    __syncthreads();
    for (int i = t; i < NBUCK_PAD; i += 256) {
        int v = c[i];
        if (v) atomicAdd(bcnt + i, v);
    }
    __threadfence();
    if (t == 0) lastFlag = (atomicAdd(done, 1) == (int)gridDim.x - 1);
    __syncthreads();
    if (!lastFlag) return;
    int v0 = bcnt[t * 4 + 0], v1 = bcnt[t * 4 + 1];
    int v2 = bcnt[t * 4 + 2], v3 = bcnt[t * 4 + 3];
    int local = v0 + v1 + v2 + v3;
    tsum[t] = local;
    __syncthreads();
    for (int off = 1; off < 256; off <<= 1) {
        int u = (t >= off) ? tsum[t - off] : 0;
        __syncthreads();
        tsum[t] += u;
        __syncthreads();
    }
    int p = tsum[t] - local;     // exclusive over threads
    bbase[t * 4 + 0] = p; bcur[t * 4 + 0] = p; p += v0;
    bbase[t * 4 + 1] = p; bcur[t * 4 + 1] = p; p += v1;
    bbase[t * 4 + 2] = p; bcur[t * 4 + 2] = p; p += v2;
    bbase[t * 4 + 3] = p; bcur[t * 4 + 3] = p; p += v3;
    if (t == 255) bbase[NBUCK_PAD] = p;
}

// ebuf element: src (17 bits) | dst_low7 << 17
__global__ __launch_bounds__(256) void k_part(const int* __restrict__ srcp,
                                              const int* __restrict__ dstp,
                                              int* __restrict__ bcur,
                                              unsigned* __restrict__ ebuf) {
    __shared__ int cnt[NBUCK_PAD];
    __shared__ int gbase[NBUCK_PAD];
    int t = threadIdx.x;
    for (int i = t; i < NBUCK_PAD; i += 256) cnt[i] = 0;
    int e0 = blockIdx.x * PART_CHUNK;
    int e1 = min(e0 + PART_CHUNK, E_EDGES);
    __syncthreads();
    for (int i = e0 + t; i < e1; i += 256)
        atomicAdd(&cnt[dstp[i] >> BUCK_SHIFT], 1);
    __syncthreads();
    for (int b = t; b < NBUCK_PAD; b += 256) {
        int c = cnt[b];
        gbase[b] = c ? atomicAdd(bcur + b, c) : 0;
        cnt[b] = 0;
    }
    __syncthreads();
    for (int i = e0 + t; i < e1; i += 256) {
        int d = dstp[i];
        int b = d >> BUCK_SHIFT;
        int pos = gbase[b] + atomicAdd(&cnt[b], 1);
        ebuf[pos] = (unsigned)srcp[i] | ((unsigned)(d & 127) << 17);
    }
}

__global__ __launch_bounds__(256) void k_fin(const int* __restrict__ bbase,
                                             const unsigned* __restrict__ ebuf,
                                             int* __restrict__ row,
                                             int* __restrict__ ssrc) {
    __shared__ int cnt[NODES_PER_BUCK];
    __shared__ int sc[NODES_PER_BUCK];
    __shared__ int rbase[NODES_PER_BUCK];
    int t = threadIdx.x;
    int b = blockIdx.x;
    int start = bbase[b], end = bbase[b + 1];
    int nb0 = b << BUCK_SHIFT;
    if (t < NODES_PER_BUCK) cnt[t] = 0;
    __syncthreads();
    for (int i = start + t; i < end; i += 256)
        atomicAdd(&cnt[ebuf[i] >> 17], 1);
    __syncthreads();
    if (t < NODES_PER_BUCK) sc[t] = cnt[t];
    __syncthreads();
    for (int off = 1; off < NODES_PER_BUCK; off <<= 1) {
        int v = (t < NODES_PER_BUCK && t >= off) ? sc[t - off] : 0;
        __syncthreads();
        if (t < NODES_PER_BUCK) sc[t] += v;
        __syncthreads();
    }
    if (t < NODES_PER_BUCK) {
        int rb = start + sc[t] - cnt[t];
        rbase[t] = rb;
        int n = nb0 + t;
        if (n < N_NODES) row[n] = rb;
        cnt[t] = 0;
    }
    if (b == NBUCK - 1 && t == 0) row[N_NODES] = E_EDGES;
    __syncthreads();
    for (int i = start + t; i < end; i += 256) {
        unsigned p = ebuf[i];
        int l = (int)(p >> 17);
        int slot = rbase[l] + atomicAdd(&cnt[l], 1);
        ssrc[slot] = (int)(p & 0x1FFFFu);
    }
}

// ---- fused aggregation: 8 nodes per wave, 8 lanes per node.
//      Each group walks its node's edges serially (unroll2, 16 loads in
//      flight per wave). No cross-group merges; LN reduces over 8 lanes. ----
__global__ __launch_bounds__(256) void k_gat_agg(
        const int* __restrict__ row, const int* __restrict__ ssrc,
        const float* __restrict__ as_, const float* __restrict__ ad_,
        const unsigned* __restrict__ hlb, const float* __restrict__ hres,
        const float* __restrict__ bg, const float* __restrict__ g,
        const float* __restrict__ b, float* __restrict__ hout,
        const float* __restrict__ Wout, const float* __restrict__ bout,
        float* __restrict__ out, int last) {
    int gid = blockIdx.x * blockDim.x + threadIdx.x;
    int lane = threadIdx.x & 63;
    int grp = lane >> 3;          // 0..7: node within wave
    int q   = lane & 7;           // channels 8q..8q+7
    int n = (gid >> 6) * 8 + grp;
    if (n >= N_NODES) return;
    int head = q >> 1;
    const char* hlbc = (const char*)hlb;   // row stride 128 B
    const char* asc  = (const char*)as_;   // row stride 16 B
    unsigned nb = (unsigned)n;
    unsigned qb = (unsigned)q * 16u;
    unsigned hb = (unsigned)head * 4u;
    float adh = *(const float*)((const char*)ad_ + (nb * 16u + hb));
    // self loop
    float w = lrexp2(*(const float*)(asc + (nb * 16u + hb)) + adh);
    f2v w2; w2.x = w; w2.y = w;
    uint4 u = *(const uint4*)(hlbc + (nb * 128u + qb));
    f2v acc0 = w2 * unp2(u.x);
    f2v acc1 = w2 * unp2(u.y);
    f2v acc2 = w2 * unp2(u.z);
    f2v acc3 = w2 * unp2(u.w);
    float z = w;
    int j = row[n];
    int jend = row[n + 1];
    for (; j + 1 < jend; j += 2) {
        unsigned s0 = (unsigned)ssrc[j], s1 = (unsigned)ssrc[j + 1];
        float wa = lrexp2(*(const float*)(asc + (s0 * 16u + hb)) + adh);
        float wb = lrexp2(*(const float*)(asc + (s1 * 16u + hb)) + adh);
        uint4 ua = *(const uint4*)(hlbc + (s0 * 128u + qb));
        uint4 ub = *(const uint4*)(hlbc + (s1 * 128u + qb));
        f2v wa2; wa2.x = wa; wa2.y = wa;
        f2v wb2; wb2.x = wb; wb2.y = wb;
        acc0 += wa2 * unp2(ua.x); acc1 += wa2 * unp2(ua.y);
        acc2 += wa2 * unp2(ua.z); acc3 += wa2 * unp2(ua.w);
        acc0 += wb2 * unp2(ub.x); acc1 += wb2 * unp2(ub.y);
        acc2 += wb2 * unp2(ub.z); acc3 += wb2 * unp2(ub.w);
        z += wa + wb;
    }
    if (j < jend) {
        unsigned s0 = (unsigned)ssrc[j];
        float wa = lrexp2(*(const float*)(asc + (s0 * 16u + hb)) + adh);
        uint4 ua = *(const uint4*)(hlbc + (s0 * 128u + qb));
        f2v wa2; wa2.x = wa; wa2.y = wa;
        acc0 += wa2 * unp2(ua.x); acc1 += wa2 * unp2(ua.y);
        acc2 += wa2 * unp2(ua.z); acc3 += wa2 * unp2(ua.w);
        z += wa;
    }
    float rz = 1.f / (z + 1e-16f);
    float4 bg0 = ((const float4*)bg)[2 * q];
    float4 bg1 = ((const float4*)bg)[2 * q + 1];
    float v[8];
    v[0] = acc0.x * rz + bg0.x; v[1] = acc0.y * rz + bg0.y;
    v[2] = acc1.x * rz + bg0.z; v[3] = acc1.y * rz + bg0.w;
    v[4] = acc2.x * rz + bg1.x; v[5] = acc2.y * rz + bg1.y;
    v[6] = acc3.x * rz + bg1.z; v[7] = acc3.y * rz + bg1.w;
    float ssum = 0.f;
    #pragma unroll
    for (int i = 0; i < 8; ++i) ssum += v[i];
    #pragma unroll
    for (int off = 1; off < 8; off <<= 1) ssum += __shfl_xor(ssum, off);
    float mu = ssum * (1.f / 64.f);
    float vs = 0.f;
    #pragma unroll
    for (int i = 0; i < 8; ++i) { v[i] -= mu; vs += v[i] * v[i]; }
    #pragma unroll
    for (int off = 1; off < 8; off <<= 1) vs += __shfl_xor(vs, off);
    float rstd = rsqrtf(vs * (1.f / 64.f) + LN_EPS);
    float4 g0 = ((const float4*)g)[2 * q];
    float4 g1 = ((const float4*)g)[2 * q + 1];
    float4 b0 = ((const float4*)b)[2 * q];
    float4 b1 = ((const float4*)b)[2 * q + 1];
    float4 h0 = ((const float4*)hres)[(size_t)n * 16 + 2 * q];
    float4 h1 = ((const float4*)hres)[(size_t)n * 16 + 2 * q + 1];
    float y[8];
    y[0] = fmaxf(v[0] * rstd * g0.x + b0.x, 0.f) + h0.x;
    y[1] = fmaxf(v[1] * rstd * g0.y + b0.y, 0.f) + h0.y;
    y[2] = fmaxf(v[2] * rstd * g0.z + b0.z, 0.f) + h0.z;
    y[3] = fmaxf(v[3] * rstd * g0.w + b0.w, 0.f) + h0.w;
    y[4] = fmaxf(v[4] * rstd * g1.x + b1.x, 0.f) + h1.x;
    y[5] = fmaxf(v[5] * rstd * g1.y + b1.y, 0.f) + h1.y;
    y[6] = fmaxf(v[6] * rstd * g1.z + b1.z, 0.f) + h1.z;
    y[7] = fmaxf(v[7] * rstd * g1.w + b1.w, 0.f) + h1.w;
    if (!last) {
        float4 o0; o0.x = y[0]; o0.y = y[1]; o0.z = y[2]; o0.w = y[3];
        float4 o1; o1.x = y[4]; o1.y = y[5]; o1.z = y[6]; o1.w = y[7];
        ((float4*)hout)[(size_t)n * 16 + 2 * q] = o0;
        ((float4*)hout)[(size_t)n * 16 + 2 * q + 1] = o1;
    } else {
        float4 w0 = ((const float4*)Wout)[2 * q];
        float4 w1 = ((const float4*)Wout)[2 * q + 1];
        float pp = y[0] * w0.x + y[1] * w0.y + y[2] * w0.z + y[3] * w0.w
                 + y[4] * w1.x + y[5] * w1.y + y[6] * w1.z + y[7] * w1.w;
        #pragma unroll
        for (int off = 1; off < 8; off <<= 1) pp += __shfl_xor(pp, off);
        if (q == 0) out[n] = pp + bout[0];
    }
}

extern "C" void kernel_launch(void* const* d_in, const int* in_sizes, int n_in,
                              void* d_out, int out_size, void* d_ws, size_t ws_size,
                              hipStream_t stream) {
    const float* x     = (const float*)d_in[0];
    const int*   ei    = (const int*)  d_in[1];
    const float* Win   = (const float*)d_in[2];
    const float* bin_  = (const float*)d_in[3];
    const float* Wg    = (const float*)d_in[4];
    const float* att_s = (const float*)d_in[5];
    const float* att_d = (const float*)d_in[6];
    const float* bg    = (const float*)d_in[7];
    const float* lng   = (const float*)d_in[8];
    const float* lnb   = (const float*)d_in[9];
    const float* Wout  = (const float*)d_in[10];
    const float* bout  = (const float*)d_in[11];
    float* out = (float*)d_out;

    float* hA   = (float*)d_ws;                        // h (layer input / residual)
    float* hC   = hA + (size_t)N_NODES * 64;           // h (layer output)
    unsigned* hlb = (unsigned*)(hC + (size_t)N_NODES * 64);  // bf16x2 [N][32]
    float* as_  = (float*)(hlb + (size_t)N_NODES * 32);
    float* ad_  = as_ + (size_t)N_NODES * 4;
    int* row    = (int*)(ad_ + (size_t)N_NODES * 4);   // N+1
    int* bcnt   = row + (N_NODES + 1);                 // 1024
    int* done   = bcnt + NBUCK_PAD;                    // 1
    int* bbase  = done + 1;                            // 1025
    int* bcur   = bbase + (NBUCK_PAD + 1);             // 1024
    int* ssrc   = bcur + NBUCK_PAD;                    // E
    unsigned* ebuf = (unsigned*)(ssrc + E_EDGES);      // E packed

    const int* srcp = ei;
    const int* dstp = ei + E_EDGES;

    hipMemsetAsync(bcnt, 0, (NBUCK_PAD + 1) * sizeof(int), stream);   // bcnt + done
    k_bhist_scan<<<HIST_BLOCKS, 256, 0, stream>>>(dstp, bcnt, done, bbase, bcur);
    k_part<<<(E_EDGES + PART_CHUNK - 1) / PART_CHUNK, 256, 0, stream>>>(srcp, dstp, bcur, ebuf);
    k_fin<<<NBUCK, 256, 0, stream>>>(bbase, ebuf, row, ssrc);

    k_in_proj<<<N_NODES / 32, 256, 0, stream>>>(x, Win, bin_, hA);

    const int aggBlocks = (N_NODES + 31) / 32;   // 8 nodes/wave, 4 waves/block
    for (int L = 0; L < 3; ++L) {
        k_gat_lin<<<N_NODES / 32, 256, 0, stream>>>(hA, Wg + L * 64 * 64,
                                            att_s + L * 64, att_d + L * 64,
                                            hlb, as_, ad_);
        k_gat_agg<<<aggBlocks, 256, 0, stream>>>(row, ssrc, as_, ad_, hlb, hA,
                                                 bg + L * 64, lng + L * 64, lnb + L * 64,
                                                 hC, Wout, bout, out, (L == 2) ? 1 : 0);
        float* t = hA; hA = hC; hC = t;
    }
}

// Round 12
// 295.450 us; speedup vs baseline: 1.1953x; 1.0679x over previous
//
#include <hip/hip_runtime.h>
#include <hip/hip_bf16.h>

#define N_NODES 100000
#define E_EDGES 1600000
#define IN_DIM  128
#define HID     64
#define HEADS   4
#define NEG_SLOPE 0.2f
#define LN_EPS  1e-5f
#define LOG2E   1.4426950408889634f

#define BUCK_SHIFT 7
#define NODES_PER_BUCK 128
#define NBUCK ((N_NODES + NODES_PER_BUCK - 1) / NODES_PER_BUCK)   // 782
#define NBUCK_PAD 1024
#define PART_CHUNK 8192
#define HIST_BLOCKS 256

typedef float f2v __attribute__((ext_vector_type(2)));

__device__ __forceinline__ f2v unp2(unsigned u) {
    f2v r; r.x = __uint_as_float(u << 16); r.y = __uint_as_float(u & 0xffff0000u); return r;
}
__device__ __forceinline__ unsigned packbf2(float a, float b) {
    unsigned ua = __float_as_uint(a), ub = __float_as_uint(b);
    ua += 0x7fffu + ((ua >> 16) & 1u);
    ub += 0x7fffu + ((ub >> 16) & 1u);
    return (ua >> 16) | (ub & 0xffff0000u);
}
// e pre-scaled by LOG2E; weight = exp(lrelu(e_orig)) = 2^(lrelu(e))
__device__ __forceinline__ float lrexp2(float e) {
    return __builtin_amdgcn_exp2f(fmaxf(e, NEG_SLOPE * e));
}

// ---- kernel A: h0 = relu(x @ Win + bin). Tiled GEMM, 32 nodes/block.
//      K-chunked weight staging: 33 KB LDS -> 4 blocks/CU. ----
__global__ __launch_bounds__(256) void k_in_proj(
        const float* __restrict__ x, const float* __restrict__ W,
        const float* __restrict__ bias, float* __restrict__ h) {
    __shared__ float Xs[32][132];     // 16.9 KB
    __shared__ float Ws[64][64];      // 16 KB (double-pass)
    int t = threadIdx.x;
    int base = blockIdx.x * 32;
    const float4* X4 = (const float4*)(x + (size_t)base * IN_DIM);
    #pragma unroll
    for (int i = 0; i < 4; ++i) {
        int f = t + 256 * i;
        ((float4*)&Xs[f >> 5][0])[f & 31] = X4[f];
    }
    const float4* W4 = (const float4*)W;
    float4* Ws4 = (float4*)&Ws[0][0];
    #pragma unroll
    for (int i = 0; i < 4; ++i) Ws4[t + 256 * i] = W4[t + 256 * i];
    __syncthreads();
    int r = t >> 4;               // rows {r, r+16}
    int c = (t & 15) * 4;         // cols c..c+3
    float4 bb = *(const float4*)(bias + c);
    float4 acc0 = bb, acc1 = bb;
    #pragma unroll 8
    for (int k = 0; k < 64; ++k) {
        float a0 = Xs[r][k];
        float a1 = Xs[r + 16][k];
        float4 b = *(const float4*)&Ws[k][c];
        acc0.x += a0 * b.x; acc0.y += a0 * b.y; acc0.z += a0 * b.z; acc0.w += a0 * b.w;
        acc1.x += a1 * b.x; acc1.y += a1 * b.y; acc1.z += a1 * b.z; acc1.w += a1 * b.w;
    }
    __syncthreads();   // all reads of Ws chunk 0 done
    #pragma unroll
    for (int i = 0; i < 4; ++i) Ws4[t + 256 * i] = W4[1024 + t + 256 * i];
    __syncthreads();
    #pragma unroll 8
    for (int k = 0; k < 64; ++k) {
        float a0 = Xs[r][64 + k];
        float a1 = Xs[r + 16][64 + k];
        float4 b = *(const float4*)&Ws[k][c];
        acc0.x += a0 * b.x; acc0.y += a0 * b.y; acc0.z += a0 * b.z; acc0.w += a0 * b.w;
        acc1.x += a1 * b.x; acc1.y += a1 * b.y; acc1.z += a1 * b.z; acc1.w += a1 * b.w;
    }
    acc0.x = fmaxf(acc0.x, 0.f); acc0.y = fmaxf(acc0.y, 0.f);
    acc0.z = fmaxf(acc0.z, 0.f); acc0.w = fmaxf(acc0.w, 0.f);
    acc1.x = fmaxf(acc1.x, 0.f); acc1.y = fmaxf(acc1.y, 0.f);
    acc1.z = fmaxf(acc1.z, 0.f); acc1.w = fmaxf(acc1.w, 0.f);
    *(float4*)(h + (size_t)(base + r) * HID + c) = acc0;
    *(float4*)(h + (size_t)(base + r + 16) * HID + c) = acc1;
}

// ---- kernel B: hl(bf16) = h @ Wg + per-(node,head) alpha reductions ----
__global__ __launch_bounds__(256) void k_gat_lin(
        const float* __restrict__ h, const float* __restrict__ W,
        const float* __restrict__ as_w, const float* __restrict__ ad_w,
        unsigned* __restrict__ hlb, float* __restrict__ as_o, float* __restrict__ ad_o) {
    __shared__ float Xs[32][68];
    __shared__ float Ws[64][64];
    int t = threadIdx.x;
    const float4* W4 = (const float4*)W;
    float4* Ws4 = (float4*)&Ws[0][0];
    #pragma unroll
    for (int i = 0; i < 4; ++i) Ws4[t + 256 * i] = W4[t + 256 * i];
    int base = blockIdx.x * 32;
    const float4* X4 = (const float4*)(h + (size_t)base * HID);
    #pragma unroll
    for (int i = 0; i < 2; ++i) {
        int f = t + 256 * i;
        ((float4*)&Xs[f >> 4][0])[f & 15] = X4[f];
    }
    __syncthreads();
    int r = t >> 4;
    int c = (t & 15) * 4;
    float4 acc0 = {0.f, 0.f, 0.f, 0.f}, acc1 = {0.f, 0.f, 0.f, 0.f};
    #pragma unroll 8
    for (int k = 0; k < 64; ++k) {
        float a0 = Xs[r][k];
        float a1 = Xs[r + 16][k];
        float4 b = *(const float4*)&Ws[k][c];
        acc0.x += a0 * b.x; acc0.y += a0 * b.y; acc0.z += a0 * b.z; acc0.w += a0 * b.w;
        acc1.x += a1 * b.x; acc1.y += a1 * b.y; acc1.z += a1 * b.z; acc1.w += a1 * b.w;
    }
    uint2 p0, p1;
    p0.x = packbf2(acc0.x, acc0.y); p0.y = packbf2(acc0.z, acc0.w);
    p1.x = packbf2(acc1.x, acc1.y); p1.y = packbf2(acc1.z, acc1.w);
    ((uint2*)hlb)[(size_t)(base + r) * 16 + (c >> 2)] = p0;
    ((uint2*)hlb)[(size_t)(base + r + 16) * 16 + (c >> 2)] = p1;
    float4 A = *(const float4*)(as_w + c);
    float4 D = *(const float4*)(ad_w + c);
    A.x *= LOG2E; A.y *= LOG2E; A.z *= LOG2E; A.w *= LOG2E;
    D.x *= LOG2E; D.y *= LOG2E; D.z *= LOG2E; D.w *= LOG2E;
    float s0 = acc0.x * A.x + acc0.y * A.y + acc0.z * A.z + acc0.w * A.w;
    float d0 = acc0.x * D.x + acc0.y * D.y + acc0.z * D.z + acc0.w * D.w;
    float s1 = acc1.x * A.x + acc1.y * A.y + acc1.z * A.z + acc1.w * A.w;
    float d1 = acc1.x * D.x + acc1.y * D.y + acc1.z * D.z + acc1.w * D.w;
    #pragma unroll
    for (int off = 1; off < 4; off <<= 1) {
        s0 += __shfl_xor(s0, off); d0 += __shfl_xor(d0, off);
        s1 += __shfl_xor(s1, off); d1 += __shfl_xor(d1, off);
    }
    if ((t & 3) == 0) {
        int head = (t & 15) >> 2;
        as_o[(size_t)(base + r) * HEADS + head] = s0;
        ad_o[(size_t)(base + r) * HEADS + head] = d0;
        as_o[(size_t)(base + r + 16) * HEADS + head] = s1;
        ad_o[(size_t)(base + r + 16) * HEADS + head] = d1;
    }
}

// ---- CSR build: merged histogram + scan (last-block trick) ----
__global__ __launch_bounds__(256) void k_bhist_scan(
        const int* __restrict__ dstp, int* __restrict__ bcnt,
        int* __restrict__ done, int* __restrict__ bbase, int* __restrict__ bcur) {
    __shared__ int c[NBUCK_PAD];
    __shared__ int tsum[256];
    __shared__ int lastFlag;
    int t = threadIdx.x;
    for (int i = t; i < NBUCK_PAD; i += 256) c[i] = 0;
    __syncthreads();
    for (int i = blockIdx.x * 256 + t; i < E_EDGES; i += gridDim.x * 256)
        atomicAdd(&c[dstp[i] >> BUCK_SHIFT], 1);
    __syncthreads();
    for (int i = t; i < NBUCK_PAD; i += 256) {
        int v = c[i];
        if (v) atomicAdd(bcnt + i, v);
    }
    __threadfence();
    if (t == 0) lastFlag = (atomicAdd(done, 1) == (int)gridDim.x - 1);
    __syncthreads();
    if (!lastFlag) return;
    int v0 = bcnt[t * 4 + 0], v1 = bcnt[t * 4 + 1];
    int v2 = bcnt[t * 4 + 2], v3 = bcnt[t * 4 + 3];
    int local = v0 + v1 + v2 + v3;
    tsum[t] = local;
    __syncthreads();
    for (int off = 1; off < 256; off <<= 1) {
        int u = (t >= off) ? tsum[t - off] : 0;
        __syncthreads();
        tsum[t] += u;
        __syncthreads();
    }
    int p = tsum[t] - local;     // exclusive over threads
    bbase[t * 4 + 0] = p; bcur[t * 4 + 0] = p; p += v0;
    bbase[t * 4 + 1] = p; bcur[t * 4 + 1] = p; p += v1;
    bbase[t * 4 + 2] = p; bcur[t * 4 + 2] = p; p += v2;
    bbase[t * 4 + 3] = p; bcur[t * 4 + 3] = p; p += v3;
    if (t == 255) bbase[NBUCK_PAD] = p;
}

// ebuf element: src (17 bits) | dst_low7 << 17. 1024 threads/block. ----
__global__ __launch_bounds__(1024) void k_part(const int* __restrict__ srcp,
                                               const int* __restrict__ dstp,
                                               int* __restrict__ bcur,
                                               unsigned* __restrict__ ebuf) {
    __shared__ int cnt[NBUCK_PAD];
    __shared__ int gbase[NBUCK_PAD];
    int t = threadIdx.x;
    cnt[t] = 0;
    int e0 = blockIdx.x * PART_CHUNK;
    int e1 = min(e0 + PART_CHUNK, E_EDGES);
    __syncthreads();
    for (int i = e0 + t; i < e1; i += 1024)
        atomicAdd(&cnt[dstp[i] >> BUCK_SHIFT], 1);
    __syncthreads();
    {
        int c = cnt[t];
        gbase[t] = c ? atomicAdd(bcur + t, c) : 0;
        cnt[t] = 0;
    }
    __syncthreads();
    for (int i = e0 + t; i < e1; i += 1024) {
        int d = dstp[i];
        int b = d >> BUCK_SHIFT;
        int pos = gbase[b] + atomicAdd(&cnt[b], 1);
        ebuf[pos] = (unsigned)srcp[i] | ((unsigned)(d & 127) << 17);
    }
}

__global__ __launch_bounds__(256) void k_fin(const int* __restrict__ bbase,
                                             const unsigned* __restrict__ ebuf,
                                             int* __restrict__ row,
                                             int* __restrict__ ssrc) {
    __shared__ int cnt[NODES_PER_BUCK];
    __shared__ int sc[NODES_PER_BUCK];
    __shared__ int rbase[NODES_PER_BUCK];
    int t = threadIdx.x;
    int b = blockIdx.x;
    int start = bbase[b], end = bbase[b + 1];
    int nb0 = b << BUCK_SHIFT;
    if (t < NODES_PER_BUCK) cnt[t] = 0;
    __syncthreads();
    for (int i = start + t; i < end; i += 256)
        atomicAdd(&cnt[ebuf[i] >> 17], 1);
    __syncthreads();
    if (t < NODES_PER_BUCK) sc[t] = cnt[t];
    __syncthreads();
    for (int off = 1; off < NODES_PER_BUCK; off <<= 1) {
        int v = (t < NODES_PER_BUCK && t >= off) ? sc[t - off] : 0;
        __syncthreads();
        if (t < NODES_PER_BUCK) sc[t] += v;
        __syncthreads();
    }
    if (t < NODES_PER_BUCK) {
        int rb = start + sc[t] - cnt[t];
        rbase[t] = rb;
        int n = nb0 + t;
        if (n < N_NODES) row[n] = rb;
        cnt[t] = 0;
    }
    if (b == NBUCK - 1 && t == 0) row[N_NODES] = E_EDGES;
    __syncthreads();
    for (int i = start + t; i < end; i += 256) {
        unsigned p = ebuf[i];
        int l = (int)(p >> 17);
        int slot = rbase[l] + atomicAdd(&cnt[l], 1);
        ssrc[slot] = (int)(p & 0x1FFFFu);
    }
}

// ---- fused aggregation: 8 nodes per wave, 8 lanes per node, unroll4
//      (4 edges in flight per group = 32 gathers/wave). ----
__global__ __launch_bounds__(256) void k_gat_agg(
        const int* __restrict__ row, const int* __restrict__ ssrc,
        const float* __restrict__ as_, const float* __restrict__ ad_,
        const unsigned* __restrict__ hlb, const float* __restrict__ hres,
        const float* __restrict__ bg, const float* __restrict__ g,
        const float* __restrict__ b, float* __restrict__ hout,
        const float* __restrict__ Wout, const float* __restrict__ bout,
        float* __restrict__ out, int last) {
    int gid = blockIdx.x * blockDim.x + threadIdx.x;
    int lane = threadIdx.x & 63;
    int grp = lane >> 3;          // 0..7: node within wave
    int q   = lane & 7;           // channels 8q..8q+7
    int n = (gid >> 6) * 8 + grp;
    if (n >= N_NODES) return;
    int head = q >> 1;
    const char* hlbc = (const char*)hlb;   // row stride 128 B
    const char* asc  = (const char*)as_;   // row stride 16 B
    unsigned nb = (unsigned)n;
    unsigned qb = (unsigned)q * 16u;
    unsigned hb = (unsigned)head * 4u;
    float adh = *(const float*)((const char*)ad_ + (nb * 16u + hb));
    // self loop
    float w = lrexp2(*(const float*)(asc + (nb * 16u + hb)) + adh);
    f2v w2; w2.x = w; w2.y = w;
    uint4 u = *(const uint4*)(hlbc + (nb * 128u + qb));
    f2v acc0 = w2 * unp2(u.x);
    f2v acc1 = w2 * unp2(u.y);
    f2v acc2 = w2 * unp2(u.z);
    f2v acc3 = w2 * unp2(u.w);
    float z = w;
    int j = row[n];
    int jend = row[n + 1];
    for (; j + 3 < jend; j += 4) {
        unsigned s0 = (unsigned)ssrc[j],     s1 = (unsigned)ssrc[j + 1];
        unsigned s2 = (unsigned)ssrc[j + 2], s3 = (unsigned)ssrc[j + 3];
        float wa = lrexp2(*(const float*)(asc + (s0 * 16u + hb)) + adh);
        float wb = lrexp2(*(const float*)(asc + (s1 * 16u + hb)) + adh);
        float wc = lrexp2(*(const float*)(asc + (s2 * 16u + hb)) + adh);
        float wd = lrexp2(*(const float*)(asc + (s3 * 16u + hb)) + adh);
        uint4 ua = *(const uint4*)(hlbc + (s0 * 128u + qb));
        uint4 ub = *(const uint4*)(hlbc + (s1 * 128u + qb));
        uint4 uc = *(const uint4*)(hlbc + (s2 * 128u + qb));
        uint4 ud = *(const uint4*)(hlbc + (s3 * 128u + qb));
        f2v wa2; wa2.x = wa; wa2.y = wa;
        f2v wb2; wb2.x = wb; wb2.y = wb;
        f2v wc2; wc2.x = wc; wc2.y = wc;
        f2v wd2; wd2.x = wd; wd2.y = wd;
        acc0 += wa2 * unp2(ua.x); acc1 += wa2 * unp2(ua.y);
        acc2 += wa2 * unp2(ua.z); acc3 += wa2 * unp2(ua.w);
        acc0 += wb2 * unp2(ub.x); acc1 += wb2 * unp2(ub.y);
        acc2 += wb2 * unp2(ub.z); acc3 += wb2 * unp2(ub.w);
        acc0 += wc2 * unp2(uc.x); acc1 += wc2 * unp2(uc.y);
        acc2 += wc2 * unp2(uc.z); acc3 += wc2 * unp2(uc.w);
        acc0 += wd2 * unp2(ud.x); acc1 += wd2 * unp2(ud.y);
        acc2 += wd2 * unp2(ud.z); acc3 += wd2 * unp2(ud.w);
        z += wa + wb + wc + wd;
    }
    for (; j < jend; ++j) {
        unsigned s0 = (unsigned)ssrc[j];
        float wa = lrexp2(*(const float*)(asc + (s0 * 16u + hb)) + adh);
        uint4 ua = *(const uint4*)(hlbc + (s0 * 128u + qb));
        f2v wa2; wa2.x = wa; wa2.y = wa;
        acc0 += wa2 * unp2(ua.x); acc1 += wa2 * unp2(ua.y);
        acc2 += wa2 * unp2(ua.z); acc3 += wa2 * unp2(ua.w);
        z += wa;
    }
    float rz = 1.f / (z + 1e-16f);
    float4 bg0 = ((const float4*)bg)[2 * q];
    float4 bg1 = ((const float4*)bg)[2 * q + 1];
    float v[8];
    v[0] = acc0.x * rz + bg0.x; v[1] = acc0.y * rz + bg0.y;
    v[2] = acc1.x * rz + bg0.z; v[3] = acc1.y * rz + bg0.w;
    v[4] = acc2.x * rz + bg1.x; v[5] = acc2.y * rz + bg1.y;
    v[6] = acc3.x * rz + bg1.z; v[7] = acc3.y * rz + bg1.w;
    float ssum = 0.f;
    #pragma unroll
    for (int i = 0; i < 8; ++i) ssum += v[i];
    #pragma unroll
    for (int off = 1; off < 8; off <<= 1) ssum += __shfl_xor(ssum, off);
    float mu = ssum * (1.f / 64.f);
    float vs = 0.f;
    #pragma unroll
    for (int i = 0; i < 8; ++i) { v[i] -= mu; vs += v[i] * v[i]; }
    #pragma unroll
    for (int off = 1; off < 8; off <<= 1) vs += __shfl_xor(vs, off);
    float rstd = rsqrtf(vs * (1.f / 64.f) + LN_EPS);
    float4 g0 = ((const float4*)g)[2 * q];
    float4 g1 = ((const float4*)g)[2 * q + 1];
    float4 b0 = ((const float4*)b)[2 * q];
    float4 b1 = ((const float4*)b)[2 * q + 1];
    float4 h0 = ((const float4*)hres)[(size_t)n * 16 + 2 * q];
    float4 h1 = ((const float4*)hres)[(size_t)n * 16 + 2 * q + 1];
    float y[8];
    y[0] = fmaxf(v[0] * rstd * g0.x + b0.x, 0.f) + h0.x;
    y[1] = fmaxf(v[1] * rstd * g0.y + b0.y, 0.f) + h0.y;
    y[2] = fmaxf(v[2] * rstd * g0.z + b0.z, 0.f) + h0.z;
    y[3] = fmaxf(v[3] * rstd * g0.w + b0.w, 0.f) + h0.w;
    y[4] = fmaxf(v[4] * rstd * g1.x + b1.x, 0.f) + h1.x;
    y[5] = fmaxf(v[5] * rstd * g1.y + b1.y, 0.f) + h1.y;
    y[6] = fmaxf(v[6] * rstd * g1.z + b1.z, 0.f) + h1.z;
    y[7] = fmaxf(v[7] * rstd * g1.w + b1.w, 0.f) + h1.w;
    if (!last) {
        float4 o0; o0.x = y[0]; o0.y = y[1]; o0.z = y[2]; o0.w = y[3];
        float4 o1; o1.x = y[4]; o1.y = y[5]; o1.z = y[6]; o1.w = y[7];
        ((float4*)hout)[(size_t)n * 16 + 2 * q] = o0;
        ((float4*)hout)[(size_t)n * 16 + 2 * q + 1] = o1;
    } else {
        float4 w0 = ((const float4*)Wout)[2 * q];
        float4 w1 = ((const float4*)Wout)[2 * q + 1];
        float pp = y[0] * w0.x + y[1] * w0.y + y[2] * w0.z + y[3] * w0.w
                 + y[4] * w1.x + y[5] * w1.y + y[6] * w1.z + y[7] * w1.w;
        #pragma unroll
        for (int off = 1; off < 8; off <<= 1) pp += __shfl_xor(pp, off);
        if (q == 0) out[n] = pp + bout[0];
    }
}

extern "C" void kernel_launch(void* const* d_in, const int* in_sizes, int n_in,
                              void* d_out, int out_size, void* d_ws, size_t ws_size,
                              hipStream_t stream) {
    const float* x     = (const float*)d_in[0];
    const int*   ei    = (const int*)  d_in[1];
    const float* Win   = (const float*)d_in[2];
    const float* bin_  = (const float*)d_in[3];
    const float* Wg    = (const float*)d_in[4];
    const float* att_s = (const float*)d_in[5];
    const float* att_d = (const float*)d_in[6];
    const float* bg    = (const float*)d_in[7];
    const float* lng   = (const float*)d_in[8];
    const float* lnb   = (const float*)d_in[9];
    const float* Wout  = (const float*)d_in[10];
    const float* bout  = (const float*)d_in[11];
    float* out = (float*)d_out;

    float* hA   = (float*)d_ws;                        // h (layer input / residual)
    float* hC   = hA + (size_t)N_NODES * 64;           // h (layer output)
    unsigned* hlb = (unsigned*)(hC + (size_t)N_NODES * 64);  // bf16x2 [N][32]
    float* as_  = (float*)(hlb + (size_t)N_NODES * 32);
    float* ad_  = as_ + (size_t)N_NODES * 4;
    int* row    = (int*)(ad_ + (size_t)N_NODES * 4);   // N+1
    int* bcnt   = row + (N_NODES + 1);                 // 1024
    int* done   = bcnt + NBUCK_PAD;                    // 1
    int* bbase  = done + 1;                            // 1025
    int* bcur   = bbase + (NBUCK_PAD + 1);             // 1024
    int* ssrc   = bcur + NBUCK_PAD;                    // E
    unsigned* ebuf = (unsigned*)(ssrc + E_EDGES);      // E packed

    const int* srcp = ei;
    const int* dstp = ei + E_EDGES;

    hipMemsetAsync(bcnt, 0, (NBUCK_PAD + 1) * sizeof(int), stream);   // bcnt + done
    k_bhist_scan<<<HIST_BLOCKS, 256, 0, stream>>>(dstp, bcnt, done, bbase, bcur);
    k_part<<<(E_EDGES + PART_CHUNK - 1) / PART_CHUNK, 1024, 0, stream>>>(srcp, dstp, bcur, ebuf);
    k_fin<<<NBUCK, 256, 0, stream>>>(bbase, ebuf, row, ssrc);

    k_in_proj<<<N_NODES / 32, 256, 0, stream>>>(x, Win, bin_, hA);

    const int aggBlocks = (N_NODES + 31) / 32;   // 8 nodes/wave, 4 waves/block
    for (int L = 0; L < 3; ++L) {
        k_gat_lin<<<N_NODES / 32, 256, 0, stream>>>(hA, Wg + L * 64 * 64,
                                            att_s + L * 64, att_d + L * 64,
                                            hlb, as_, ad_);
        k_gat_agg<<<aggBlocks, 256, 0, stream>>>(row, ssrc, as_, ad_, hlb, hA,
                                                 bg + L * 64, lng + L * 64, lnb + L * 64,
                                                 hC, Wout, bout, out, (L == 2) ? 1 : 0);
        float* t = hA; hA = hC; hC = t;
    }
}